// Round 13
// baseline (427.955 us; speedup 1.0000x reference)
//
#include <hip/hip_runtime.h>

// Sizes fixed by the reference.
#define BB 4
#define SS 4096
#define DM 1024
#define HID 64
#define KTOP 204
static constexpr size_t PATTERN_N = (size_t)BB * SS * SS;  // 67108864

// ===== ATTRIBUTION PROBE: internal repeats (idempotent, kept live) =====
#define REP2 10  // k2_topk
#define REP3 4   // k3_pattern (both variants)

typedef float f4 __attribute__((ext_vector_type(4)));
typedef float f32x4 __attribute__((ext_vector_type(4)));
typedef _Float16 h8v __attribute__((ext_vector_type(8)));
typedef unsigned long long ull2 __attribute__((ext_vector_type(2)));

// d_out scratch layout (float offsets), all < PATTERN_N:
#define SCORES_OFF 0
#define WHF_OFF 16384
#define WLF_OFF 49152

// ---------------------------------------------------------------------------
// K0: W1 -> fp16 hi/lo MFMA B-fragments, scaled by 1024 (verified absmax=0).
// ---------------------------------------------------------------------------
__global__ __launch_bounds__(256) void k0_wconv(
    const float* __restrict__ W1, _Float16* __restrict__ whf,
    _Float16* __restrict__ wlf) {
  const int gid = blockIdx.x * 256 + threadIdx.x;  // 8192 total
  const int l = gid & 63;
  const int nt = (gid >> 6) & 3;
  const int k0 = gid >> 8;  // 0..31
  const int kb = k0 * 32 + (l >> 4) * 8;
  const int n = nt * 16 + (l & 15);
  h8v hi, lo;
#pragma unroll
  for (int j = 0; j < 8; ++j) {
    float w = W1[(size_t)(kb + j) * HID + n] * 1024.f;
    _Float16 h = (_Float16)w;
    hi[j] = h;
    lo[j] = (_Float16)((w - (float)h) * 4096.f);
  }
  reinterpret_cast<h8v*>(whf)[(k0 * 4 + nt) * 64 + l] = hi;
  reinterpret_cast<h8v*>(wlf)[(k0 * 4 + nt) * 64 + l] = lo;
}

// ---------------------------------------------------------------------------
// K1: R7 exact: 128 blocks x 4 waves; fp16 hi/lo 3-MFMA fp32 emulation.
// ---------------------------------------------------------------------------
__global__ __launch_bounds__(256) void k1_mfma(
    const float* __restrict__ emb, const _Float16* __restrict__ whf,
    const _Float16* __restrict__ wlf, const float* __restrict__ b1,
    const float* __restrict__ W2, const float* __restrict__ b2,
    float* __restrict__ scores) {
  const int tid = threadIdx.x;
  const int l = tid & 63;
  const int wv = tid >> 6;
  const int tokw = blockIdx.x * 128 + wv * 32;  // wave's 32 tokens
  const int lrow = l & 15;
  const int lk8 = (l >> 4) * 8;

  const float* __restrict__ ap0 = emb + (size_t)(tokw + lrow) * DM + lk8;
  const float* __restrict__ ap1 = emb + (size_t)(tokw + 16 + lrow) * DM + lk8;
  const h8v* __restrict__ bhp = reinterpret_cast<const h8v*>(whf);
  const h8v* __restrict__ blp = reinterpret_cast<const h8v*>(wlf);

  f32x4 acc0[2][4], acc1[2][4];
#pragma unroll
  for (int mt = 0; mt < 2; ++mt)
#pragma unroll
    for (int nt = 0; nt < 4; ++nt) {
      acc0[mt][nt] = (f32x4){0.f, 0.f, 0.f, 0.f};
      acc1[mt][nt] = (f32x4){0.f, 0.f, 0.f, 0.f};
    }

  f4 a0c, a1c, a0c2, a1c2;
  h8v bhc[4], blc[4];
  a0c = *reinterpret_cast<const f4*>(ap0);
  a0c2 = *reinterpret_cast<const f4*>(ap0 + 4);
  a1c = *reinterpret_cast<const f4*>(ap1);
  a1c2 = *reinterpret_cast<const f4*>(ap1 + 4);
#pragma unroll
  for (int nt = 0; nt < 4; ++nt) {
    bhc[nt] = bhp[nt * 64 + l];
    blc[nt] = blp[nt * 64 + l];
  }

#pragma unroll 2
  for (int k0 = 0; k0 < 32; ++k0) {
    f4 a0n, a1n, a0n2, a1n2;
    h8v bhn[4], bln[4];
    if (k0 < 31) {  // prefetch next K-step
      const int koff = (k0 + 1) * 32;
      a0n = *reinterpret_cast<const f4*>(ap0 + koff);
      a0n2 = *reinterpret_cast<const f4*>(ap0 + koff + 4);
      a1n = *reinterpret_cast<const f4*>(ap1 + koff);
      a1n2 = *reinterpret_cast<const f4*>(ap1 + koff + 4);
#pragma unroll
      for (int nt = 0; nt < 4; ++nt) {
        bhn[nt] = bhp[((k0 + 1) * 4 + nt) * 64 + l];
        bln[nt] = blp[((k0 + 1) * 4 + nt) * 64 + l];
      }
    }
    h8v ah[2], al[2];
#pragma unroll
    for (int j = 0; j < 4; ++j) {
      _Float16 h;
      h = (_Float16)a0c[j];  ah[0][j] = h;
      al[0][j] = (_Float16)((a0c[j] - (float)h) * 4096.f);
      h = (_Float16)a0c2[j]; ah[0][4 + j] = h;
      al[0][4 + j] = (_Float16)((a0c2[j] - (float)h) * 4096.f);
      h = (_Float16)a1c[j];  ah[1][j] = h;
      al[1][j] = (_Float16)((a1c[j] - (float)h) * 4096.f);
      h = (_Float16)a1c2[j]; ah[1][4 + j] = h;
      al[1][4 + j] = (_Float16)((a1c2[j] - (float)h) * 4096.f);
    }
#pragma unroll
    for (int mt = 0; mt < 2; ++mt)
#pragma unroll
      for (int nt = 0; nt < 4; ++nt) {
        acc0[mt][nt] = __builtin_amdgcn_mfma_f32_16x16x32_f16(
            ah[mt], bhc[nt], acc0[mt][nt], 0, 0, 0);
        acc1[mt][nt] = __builtin_amdgcn_mfma_f32_16x16x32_f16(
            al[mt], bhc[nt], acc1[mt][nt], 0, 0, 0);
        acc1[mt][nt] = __builtin_amdgcn_mfma_f32_16x16x32_f16(
            ah[mt], blc[nt], acc1[mt][nt], 0, 0, 0);
      }
    if (k0 < 31) {
      a0c = a0n; a0c2 = a0n2; a1c = a1n; a1c2 = a1n2;
#pragma unroll
      for (int nt = 0; nt < 4; ++nt) { bhc[nt] = bhn[nt]; blc[nt] = bln[nt]; }
    }
  }

  float w2v[4], b1v[4];
#pragma unroll
  for (int nt = 0; nt < 4; ++nt) {
    w2v[nt] = W2[nt * 16 + lrow];
    b1v[nt] = b1[nt * 16 + lrow];
  }
  const float bb2 = b2[0];
#pragma unroll
  for (int mt = 0; mt < 2; ++mt)
#pragma unroll
    for (int i = 0; i < 4; ++i) {
      float p = 0.f;
#pragma unroll
      for (int nt = 0; nt < 4; ++nt) {
        float hs = (acc0[mt][nt][i] + 0x1p-12f * acc1[mt][nt][i]) * 0x1p-10f +
                   b1v[nt];
        hs = hs > 0.f ? hs : 0.f;
        p = fmaf(hs, w2v[nt], p);
      }
      p += __shfl_xor(p, 1, 64);
      p += __shfl_xor(p, 2, 64);
      p += __shfl_xor(p, 4, 64);
      p += __shfl_xor(p, 8, 64);
      if (lrow == 0)
        scores[tokw + mt * 16 + (l >> 4) * 4 + i] = p + bb2;
    }
}

// ---------------------------------------------------------------------------
// K2: u64-key rank counting (R10 structure) x REP2 (stage once, count x10).
// ---------------------------------------------------------------------------
__global__ __launch_bounds__(512) void k2_topk(
    const float* __restrict__ scores, float* __restrict__ out_idx) {
  __shared__ __align__(16) unsigned long long ku[SS];  // 32 KB keys
  __shared__ int red[512];
  const int tid = threadIdx.x;
  const int b = blockIdx.x >> 6;
  const int ic = blockIdx.x & 63;
  const float* row = scores + (size_t)b * SS;
#pragma unroll
  for (int q = 0; q < 8; ++q) {
    const int j = tid + q * 512;
    unsigned u = __builtin_bit_cast(unsigned, row[j]);
    u ^= (unsigned)((int)u >> 31) | 0x80000000u;  // monotonic map
    ku[j] = ((unsigned long long)u << 32) | (unsigned)(SS - 1 - j);
  }
  __syncthreads();
  const int il = tid & 63;
  const int part = tid >> 6;  // j-eighth (wave-uniform)
  const int i = ic * 64 + il;
  const ull2* kp = reinterpret_cast<const ull2*>(ku);
#pragma unroll 1
  for (int rep = 0; rep < REP2; ++rep) {
    asm volatile("" ::: "memory");
    const unsigned long long ki = ku[i];
    int cnt = 0;
#pragma unroll 8
    for (int m = part * 256; m < part * 256 + 256; ++m) {
      ull2 v = kp[m];  // broadcast b128 read: 2 keys
      cnt += (int)(v.x > ki) + (int)(v.y > ki);
    }
    red[tid] = cnt;
    __syncthreads();
    if (tid < 64) {
      int tot = 0;
#pragma unroll
      for (int p = 0; p < 8; ++p) tot += red[tid + p * 64];
      if (tot < KTOP) out_idx[b * KTOP + tot] = (float)(ic * 64 + tid);
    }
    __syncthreads();
  }
}

// ---------------------------------------------------------------------------
// K3a: dense pattern write, PLAIN f4 stores, 2048 blocks x 8 rows, x REP3.
// ---------------------------------------------------------------------------
__global__ __launch_bounds__(256) void k3_plain(
    const float* __restrict__ out_idx, float* __restrict__ pat) {
  __shared__ __align__(16) float mask[SS];
  const int tid = threadIdx.x;
  const int b  = blockIdx.x >> 9;            // 512 blocks per batch
  const int r0 = (blockIdx.x & 511) * 8;
  const f4 zero = (f4){0.f, 0.f, 0.f, 0.f};
#pragma unroll
  for (int q = 0; q < 4; ++q) {
    int f = tid + q * 256;
    *reinterpret_cast<f4*>(&mask[f * 4]) = zero;
  }
  __syncthreads();
  if (tid < KTOP) {
    int c = (int)out_idx[b * KTOP + tid];
    mask[c] = 1.0f / (float)KTOP;
  }
  __syncthreads();
  const f4 m0 = *reinterpret_cast<const f4*>(&mask[(tid)*4]);
  const f4 m1 = *reinterpret_cast<const f4*>(&mask[(tid + 256) * 4]);
  const f4 m2 = *reinterpret_cast<const f4*>(&mask[(tid + 512) * 4]);
  const f4 m3 = *reinterpret_cast<const f4*>(&mask[(tid + 768) * 4]);
#pragma unroll 1
  for (int rep = 0; rep < REP3; ++rep) {
    asm volatile("" ::: "memory");
    for (int r = 0; r < 8; ++r) {
      f4* p4 = reinterpret_cast<f4*>(pat + ((size_t)b * SS + r0 + r) * SS);
      p4[tid]       = m0;
      p4[tid + 256] = m1;
      p4[tid + 512] = m2;
      p4[tid + 768] = m3;
    }
  }
}

// ---------------------------------------------------------------------------
// K3b: identical geometry, NONTEMPORAL stores, x REP3. Runs last (same
// output bytes; NT variant was the verified writer in R7/R8).
// ---------------------------------------------------------------------------
__global__ __launch_bounds__(256) void k3_nt(
    const float* __restrict__ out_idx, float* __restrict__ pat) {
  __shared__ __align__(16) float mask[SS];
  const int tid = threadIdx.x;
  const int b  = blockIdx.x >> 9;
  const int r0 = (blockIdx.x & 511) * 8;
  const f4 zero = (f4){0.f, 0.f, 0.f, 0.f};
#pragma unroll
  for (int q = 0; q < 4; ++q) {
    int f = tid + q * 256;
    *reinterpret_cast<f4*>(&mask[f * 4]) = zero;
  }
  __syncthreads();
  if (tid < KTOP) {
    int c = (int)out_idx[b * KTOP + tid];
    mask[c] = 1.0f / (float)KTOP;
  }
  __syncthreads();
  const f4 m0 = *reinterpret_cast<const f4*>(&mask[(tid)*4]);
  const f4 m1 = *reinterpret_cast<const f4*>(&mask[(tid + 256) * 4]);
  const f4 m2 = *reinterpret_cast<const f4*>(&mask[(tid + 512) * 4]);
  const f4 m3 = *reinterpret_cast<const f4*>(&mask[(tid + 768) * 4]);
#pragma unroll 1
  for (int rep = 0; rep < REP3; ++rep) {
    asm volatile("" ::: "memory");
    for (int r = 0; r < 8; ++r) {
      f4* p4 = reinterpret_cast<f4*>(pat + ((size_t)b * SS + r0 + r) * SS);
      __builtin_nontemporal_store(m0, &p4[tid]);
      __builtin_nontemporal_store(m1, &p4[tid + 256]);
      __builtin_nontemporal_store(m2, &p4[tid + 512]);
      __builtin_nontemporal_store(m3, &p4[tid + 768]);
    }
  }
}

extern "C" void kernel_launch(void* const* d_in, const int* in_sizes, int n_in,
                              void* d_out, int out_size, void* d_ws,
                              size_t ws_size, hipStream_t stream) {
  const float* emb = (const float*)d_in[0];
  const float* W1  = (const float*)d_in[1];
  const float* b1  = (const float*)d_in[2];
  const float* W2  = (const float*)d_in[3];
  const float* b2  = (const float*)d_in[4];
  float* out = (float*)d_out;
  float* pat     = out;              // [B,S,S] pattern
  float* out_idx = out + PATTERN_N;  // [B,KTOP] indices as float
  float* scores = out + SCORES_OFF;
  _Float16* whf = (_Float16*)(out + WHF_OFF);
  _Float16* wlf = (_Float16*)(out + WLF_OFF);

  k0_wconv<<<dim3(32), dim3(256), 0, stream>>>(W1, whf, wlf);
  k1_mfma<<<dim3((BB * SS) / 128), dim3(256), 0, stream>>>(emb, whf, wlf, b1,
                                                           W2, b2, scores);
  k2_topk<<<dim3(BB * 64), dim3(512), 0, stream>>>(scores, out_idx);
  k3_plain<<<dim3((BB * SS) / 8), dim3(256), 0, stream>>>(out_idx, pat);
  k3_nt<<<dim3((BB * SS) / 8), dim3(256), 0, stream>>>(out_idx, pat);
}

// Round 14
// 104.101 us; speedup vs baseline: 4.1110x; 4.1110x over previous
//
#include <hip/hip_runtime.h>

// Sizes fixed by the reference.
#define BB 4
#define SS 4096
#define DM 1024
#define HID 64
#define KTOP 204
static constexpr size_t PATTERN_N = (size_t)BB * SS * SS;  // 67108864

typedef float f4 __attribute__((ext_vector_type(4)));
typedef float f32x4 __attribute__((ext_vector_type(4)));
typedef _Float16 h8v __attribute__((ext_vector_type(8)));
typedef unsigned long long ull2 __attribute__((ext_vector_type(2)));

// d_out scratch layout (float offsets), all < PATTERN_N, overwritten by K3:
#define SCORES_OFF 0
#define WHF_OFF 16384
#define WLF_OFF 49152

// ---------------------------------------------------------------------------
// K0: W1 -> fp16 hi/lo MFMA B-fragments, scaled by 1024 (verified absmax=0).
// ---------------------------------------------------------------------------
__global__ __launch_bounds__(256) void k0_wconv(
    const float* __restrict__ W1, _Float16* __restrict__ whf,
    _Float16* __restrict__ wlf) {
  const int gid = blockIdx.x * 256 + threadIdx.x;  // 8192 total
  const int l = gid & 63;
  const int nt = (gid >> 6) & 3;
  const int k0 = gid >> 8;  // 0..31
  const int kb = k0 * 32 + (l >> 4) * 8;
  const int n = nt * 16 + (l & 15);
  h8v hi, lo;
#pragma unroll
  for (int j = 0; j < 8; ++j) {
    float w = W1[(size_t)(kb + j) * HID + n] * 1024.f;
    _Float16 h = (_Float16)w;
    hi[j] = h;
    lo[j] = (_Float16)((w - (float)h) * 4096.f);
  }
  reinterpret_cast<h8v*>(whf)[(k0 * 4 + nt) * 64 + l] = hi;
  reinterpret_cast<h8v*>(wlf)[(k0 * 4 + nt) * 64 + l] = lo;
}

// ---------------------------------------------------------------------------
// K1 (CHANGED, the only change this round): full-GPU version of R7's shape.
// 512 blocks x 4 waves = 2048 waves (2/SIMD, ALL 256 CUs; R7 ran 512 waves
// on half the chip). wave = 16 tokens (1 M-tile) x 4 N-tiles — keeps the
// fp32->fp16 conversion done ONCE per token (R8's regression was 4x-dup
// conversion), halves per-wave work vs R7. Numerics identical (absmax=0
// lineage): e = eh + 2^-12 el, W1x1024 hi/lo, 3 MFMA per tile pair.
// ---------------------------------------------------------------------------
__global__ __launch_bounds__(256) void k1_mfma(
    const float* __restrict__ emb, const _Float16* __restrict__ whf,
    const _Float16* __restrict__ wlf, const float* __restrict__ b1,
    const float* __restrict__ W2, const float* __restrict__ b2,
    float* __restrict__ scores) {
  const int tid = threadIdx.x;
  const int l = tid & 63;
  const int wv = tid >> 6;
  const int tokw = blockIdx.x * 64 + wv * 16;  // wave's 16 tokens
  const int lrow = l & 15;
  const int lk8 = (l >> 4) * 8;

  const float* __restrict__ ap0 = emb + (size_t)(tokw + lrow) * DM + lk8;
  const h8v* __restrict__ bhp = reinterpret_cast<const h8v*>(whf);
  const h8v* __restrict__ blp = reinterpret_cast<const h8v*>(wlf);

  f32x4 acc0[4], acc1[4];
#pragma unroll
  for (int nt = 0; nt < 4; ++nt) {
    acc0[nt] = (f32x4){0.f, 0.f, 0.f, 0.f};
    acc1[nt] = (f32x4){0.f, 0.f, 0.f, 0.f};
  }

  f4 a0c, a0c2;
  h8v bhc[4], blc[4];
  a0c = *reinterpret_cast<const f4*>(ap0);
  a0c2 = *reinterpret_cast<const f4*>(ap0 + 4);
#pragma unroll
  for (int nt = 0; nt < 4; ++nt) {
    bhc[nt] = bhp[nt * 64 + l];
    blc[nt] = blp[nt * 64 + l];
  }

#pragma unroll 2
  for (int k0 = 0; k0 < 32; ++k0) {
    f4 a0n, a0n2;
    h8v bhn[4], bln[4];
    if (k0 < 31) {  // prefetch next K-step
      const int koff = (k0 + 1) * 32;
      a0n = *reinterpret_cast<const f4*>(ap0 + koff);
      a0n2 = *reinterpret_cast<const f4*>(ap0 + koff + 4);
#pragma unroll
      for (int nt = 0; nt < 4; ++nt) {
        bhn[nt] = bhp[((k0 + 1) * 4 + nt) * 64 + l];
        bln[nt] = blp[((k0 + 1) * 4 + nt) * 64 + l];
      }
    }
    // convert current A to fp16 hi/lo (once per token per K-step)
    h8v ah, al;
#pragma unroll
    for (int j = 0; j < 4; ++j) {
      _Float16 h;
      h = (_Float16)a0c[j];  ah[j] = h;
      al[j] = (_Float16)((a0c[j] - (float)h) * 4096.f);
      h = (_Float16)a0c2[j]; ah[4 + j] = h;
      al[4 + j] = (_Float16)((a0c2[j] - (float)h) * 4096.f);
    }
#pragma unroll
    for (int nt = 0; nt < 4; ++nt) {
      acc0[nt] = __builtin_amdgcn_mfma_f32_16x16x32_f16(
          ah, bhc[nt], acc0[nt], 0, 0, 0);
      acc1[nt] = __builtin_amdgcn_mfma_f32_16x16x32_f16(
          al, bhc[nt], acc1[nt], 0, 0, 0);
      acc1[nt] = __builtin_amdgcn_mfma_f32_16x16x32_f16(
          ah, blc[nt], acc1[nt], 0, 0, 0);
    }
    if (k0 < 31) {
      a0c = a0n; a0c2 = a0n2;
#pragma unroll
      for (int nt = 0; nt < 4; ++nt) { bhc[nt] = bhn[nt]; blc[nt] = bln[nt]; }
    }
  }

  float w2v[4], b1v[4];
#pragma unroll
  for (int nt = 0; nt < 4; ++nt) {
    w2v[nt] = W2[nt * 16 + lrow];
    b1v[nt] = b1[nt * 16 + lrow];
  }
  const float bb2 = b2[0];
#pragma unroll
  for (int i = 0; i < 4; ++i) {
    float p = 0.f;
#pragma unroll
    for (int nt = 0; nt < 4; ++nt) {
      float hs = (acc0[nt][i] + 0x1p-12f * acc1[nt][i]) * 0x1p-10f + b1v[nt];
      hs = hs > 0.f ? hs : 0.f;
      p = fmaf(hs, w2v[nt], p);
    }
    p += __shfl_xor(p, 1, 64);
    p += __shfl_xor(p, 2, 64);
    p += __shfl_xor(p, 4, 64);
    p += __shfl_xor(p, 8, 64);
    if (lrow == 0) scores[tokw + (l >> 4) * 4 + i] = p + bb2;
  }
}

// ---------------------------------------------------------------------------
// K2: u64-key rank counting (R10 exact; REP-measured count phase ~2-4 us).
// key_j = (mono(s_j)<<32) | (4095-j); rank_i = #{j: key_j > key_i} ==
// jax.lax.top_k order. 256 blocks x 512 threads, 8-way j-split.
// ---------------------------------------------------------------------------
__global__ __launch_bounds__(512) void k2_topk(
    const float* __restrict__ scores, float* __restrict__ out_idx) {
  __shared__ __align__(16) unsigned long long ku[SS];  // 32 KB keys
  __shared__ int red[512];
  const int tid = threadIdx.x;
  const int b = blockIdx.x >> 6;
  const int ic = blockIdx.x & 63;
  const float* row = scores + (size_t)b * SS;
#pragma unroll
  for (int q = 0; q < 8; ++q) {
    const int j = tid + q * 512;
    unsigned u = __builtin_bit_cast(unsigned, row[j]);
    u ^= (unsigned)((int)u >> 31) | 0x80000000u;  // monotonic map
    ku[j] = ((unsigned long long)u << 32) | (unsigned)(SS - 1 - j);
  }
  __syncthreads();
  const int il = tid & 63;
  const int part = tid >> 6;  // j-eighth (wave-uniform)
  const int i = ic * 64 + il;
  const unsigned long long ki = ku[i];
  const ull2* kp = reinterpret_cast<const ull2*>(ku);
  int cnt = 0;
#pragma unroll 8
  for (int m = part * 256; m < part * 256 + 256; ++m) {
    ull2 v = kp[m];  // broadcast b128 read: 2 keys
    cnt += (int)(v.x > ki) + (int)(v.y > ki);
  }
  red[tid] = cnt;
  __syncthreads();
  if (tid < 64) {
    int tot = 0;
#pragma unroll
    for (int p = 0; p < 8; ++p) tot += red[tid + p * 64];
    if (tot < KTOP) out_idx[b * KTOP + tot] = (float)(ic * 64 + tid);
  }
}

// ---------------------------------------------------------------------------
// K3: R10 exact (best measured): plain f4 stores, 2048 blocks x 8 rows.
// R13 A/B: plain ~38-43/pass (L3-assisted rewrite) vs NT 48.5 @5.3TB/s.
// ---------------------------------------------------------------------------
__global__ __launch_bounds__(256) void k3_pattern(
    const float* __restrict__ out_idx, float* __restrict__ pat) {
  __shared__ __align__(16) float mask[SS];
  const int tid = threadIdx.x;
  const int b  = blockIdx.x >> 9;            // 512 blocks per batch
  const int r0 = (blockIdx.x & 511) * 8;
  const f4 zero = (f4){0.f, 0.f, 0.f, 0.f};
#pragma unroll
  for (int q = 0; q < 4; ++q) {
    int f = tid + q * 256;
    *reinterpret_cast<f4*>(&mask[f * 4]) = zero;
  }
  __syncthreads();
  if (tid < KTOP) {
    int c = (int)out_idx[b * KTOP + tid];
    mask[c] = 1.0f / (float)KTOP;
  }
  __syncthreads();
  const f4 m0 = *reinterpret_cast<const f4*>(&mask[(tid)*4]);
  const f4 m1 = *reinterpret_cast<const f4*>(&mask[(tid + 256) * 4]);
  const f4 m2 = *reinterpret_cast<const f4*>(&mask[(tid + 512) * 4]);
  const f4 m3 = *reinterpret_cast<const f4*>(&mask[(tid + 768) * 4]);
  for (int r = 0; r < 8; ++r) {
    f4* p4 = reinterpret_cast<f4*>(pat + ((size_t)b * SS + r0 + r) * SS);
    p4[tid]       = m0;
    p4[tid + 256] = m1;
    p4[tid + 512] = m2;
    p4[tid + 768] = m3;
  }
}

extern "C" void kernel_launch(void* const* d_in, const int* in_sizes, int n_in,
                              void* d_out, int out_size, void* d_ws,
                              size_t ws_size, hipStream_t stream) {
  const float* emb = (const float*)d_in[0];
  const float* W1  = (const float*)d_in[1];
  const float* b1  = (const float*)d_in[2];
  const float* W2  = (const float*)d_in[3];
  const float* b2  = (const float*)d_in[4];
  float* out = (float*)d_out;
  float* pat     = out;              // [B,S,S] pattern
  float* out_idx = out + PATTERN_N;  // [B,KTOP] indices as float
  float* scores = out + SCORES_OFF;
  _Float16* whf = (_Float16*)(out + WHF_OFF);
  _Float16* wlf = (_Float16*)(out + WLF_OFF);

  k0_wconv<<<dim3(32), dim3(256), 0, stream>>>(W1, whf, wlf);
  k1_mfma<<<dim3((BB * SS) / 64), dim3(256), 0, stream>>>(emb, whf, wlf, b1,
                                                          W2, b2, scores);
  k2_topk<<<dim3(BB * 64), dim3(512), 0, stream>>>(scores, out_idx);
  k3_pattern<<<dim3((BB * SS) / 8), dim3(256), 0, stream>>>(out_idx, pat);
}

// Round 16
// 101.388 us; speedup vs baseline: 4.2210x; 1.0268x over previous
//
#include <hip/hip_runtime.h>

// Sizes fixed by the reference.
#define BB 4
#define SS 4096
#define DM 1024
#define HID 64
#define KTOP 204
static constexpr size_t PATTERN_N = (size_t)BB * SS * SS;  // 67108864

typedef float f4 __attribute__((ext_vector_type(4)));
typedef float f32x4 __attribute__((ext_vector_type(4)));
typedef _Float16 h8v __attribute__((ext_vector_type(8)));
typedef unsigned long long ull2 __attribute__((ext_vector_type(2)));

// d_out scratch layout (float offsets), all < PATTERN_N, overwritten by K3:
#define SCORES_OFF 0
#define WHF_OFF 16384
#define WLF_OFF 49152

// ---------------------------------------------------------------------------
// K0: W1 -> fp16 hi/lo MFMA B-fragments, scaled by 1024 (verified absmax=0).
// ---------------------------------------------------------------------------
__global__ __launch_bounds__(256) void k0_wconv(
    const float* __restrict__ W1, _Float16* __restrict__ whf,
    _Float16* __restrict__ wlf) {
  const int gid = blockIdx.x * 256 + threadIdx.x;  // 8192 total
  const int l = gid & 63;
  const int nt = (gid >> 6) & 3;
  const int k0 = gid >> 8;  // 0..31
  const int kb = k0 * 32 + (l >> 4) * 8;
  const int n = nt * 16 + (l & 15);
  h8v hi, lo;
#pragma unroll
  for (int j = 0; j < 8; ++j) {
    float w = W1[(size_t)(kb + j) * HID + n] * 1024.f;
    _Float16 h = (_Float16)w;
    hi[j] = h;
    lo[j] = (_Float16)((w - (float)h) * 4096.f);
  }
  reinterpret_cast<h8v*>(whf)[(k0 * 4 + nt) * 64 + l] = hi;
  reinterpret_cast<h8v*>(wlf)[(k0 * 4 + nt) * 64 + l] = lo;
}

// ---------------------------------------------------------------------------
// K1: R14 exact (full-GPU, 512 blocks x 4 waves; wave = 16 tokens x 4
// N-tiles; fp16 hi/lo 3-MFMA fp32 emulation, absmax=0 lineage). ~14 us.
// ---------------------------------------------------------------------------
__global__ __launch_bounds__(256) void k1_mfma(
    const float* __restrict__ emb, const _Float16* __restrict__ whf,
    const _Float16* __restrict__ wlf, const float* __restrict__ b1,
    const float* __restrict__ W2, const float* __restrict__ b2,
    float* __restrict__ scores) {
  const int tid = threadIdx.x;
  const int l = tid & 63;
  const int wv = tid >> 6;
  const int tokw = blockIdx.x * 64 + wv * 16;  // wave's 16 tokens
  const int lrow = l & 15;
  const int lk8 = (l >> 4) * 8;

  const float* __restrict__ ap0 = emb + (size_t)(tokw + lrow) * DM + lk8;
  const h8v* __restrict__ bhp = reinterpret_cast<const h8v*>(whf);
  const h8v* __restrict__ blp = reinterpret_cast<const h8v*>(wlf);

  f32x4 acc0[4], acc1[4];
#pragma unroll
  for (int nt = 0; nt < 4; ++nt) {
    acc0[nt] = (f32x4){0.f, 0.f, 0.f, 0.f};
    acc1[nt] = (f32x4){0.f, 0.f, 0.f, 0.f};
  }

  f4 a0c, a0c2;
  h8v bhc[4], blc[4];
  a0c = *reinterpret_cast<const f4*>(ap0);
  a0c2 = *reinterpret_cast<const f4*>(ap0 + 4);
#pragma unroll
  for (int nt = 0; nt < 4; ++nt) {
    bhc[nt] = bhp[nt * 64 + l];
    blc[nt] = blp[nt * 64 + l];
  }

#pragma unroll 2
  for (int k0 = 0; k0 < 32; ++k0) {
    f4 a0n, a0n2;
    h8v bhn[4], bln[4];
    if (k0 < 31) {  // prefetch next K-step
      const int koff = (k0 + 1) * 32;
      a0n = *reinterpret_cast<const f4*>(ap0 + koff);
      a0n2 = *reinterpret_cast<const f4*>(ap0 + koff + 4);
#pragma unroll
      for (int nt = 0; nt < 4; ++nt) {
        bhn[nt] = bhp[((k0 + 1) * 4 + nt) * 64 + l];
        bln[nt] = blp[((k0 + 1) * 4 + nt) * 64 + l];
      }
    }
    h8v ah, al;
#pragma unroll
    for (int j = 0; j < 4; ++j) {
      _Float16 h;
      h = (_Float16)a0c[j];  ah[j] = h;
      al[j] = (_Float16)((a0c[j] - (float)h) * 4096.f);
      h = (_Float16)a0c2[j]; ah[4 + j] = h;
      al[4 + j] = (_Float16)((a0c2[j] - (float)h) * 4096.f);
    }
#pragma unroll
    for (int nt = 0; nt < 4; ++nt) {
      acc0[nt] = __builtin_amdgcn_mfma_f32_16x16x32_f16(
          ah, bhc[nt], acc0[nt], 0, 0, 0);
      acc1[nt] = __builtin_amdgcn_mfma_f32_16x16x32_f16(
          al, bhc[nt], acc1[nt], 0, 0, 0);
      acc1[nt] = __builtin_amdgcn_mfma_f32_16x16x32_f16(
          ah, blc[nt], acc1[nt], 0, 0, 0);
    }
    if (k0 < 31) {
      a0c = a0n; a0c2 = a0n2;
#pragma unroll
      for (int nt = 0; nt < 4; ++nt) { bhc[nt] = bhn[nt]; blc[nt] = bln[nt]; }
    }
  }

  float w2v[4], b1v[4];
#pragma unroll
  for (int nt = 0; nt < 4; ++nt) {
    w2v[nt] = W2[nt * 16 + lrow];
    b1v[nt] = b1[nt * 16 + lrow];
  }
  const float bb2 = b2[0];
#pragma unroll
  for (int i = 0; i < 4; ++i) {
    float p = 0.f;
#pragma unroll
    for (int nt = 0; nt < 4; ++nt) {
      float hs = (acc0[nt][i] + 0x1p-12f * acc1[nt][i]) * 0x1p-10f + b1v[nt];
      hs = hs > 0.f ? hs : 0.f;
      p = fmaf(hs, w2v[nt], p);
    }
    p += __shfl_xor(p, 1, 64);
    p += __shfl_xor(p, 2, 64);
    p += __shfl_xor(p, 4, 64);
    p += __shfl_xor(p, 8, 64);
    if (lrow == 0) scores[tokw + (l >> 4) * 4 + i] = p + bb2;
  }
}

// ---------------------------------------------------------------------------
// K2: u64-key rank counting (R10 exact; count phase REP-measured ~2.5 us).
// ---------------------------------------------------------------------------
__global__ __launch_bounds__(512) void k2_topk(
    const float* __restrict__ scores, float* __restrict__ out_idx) {
  __shared__ __align__(16) unsigned long long ku[SS];  // 32 KB keys
  __shared__ int red[512];
  const int tid = threadIdx.x;
  const int b = blockIdx.x >> 6;
  const int ic = blockIdx.x & 63;
  const float* row = scores + (size_t)b * SS;
#pragma unroll
  for (int q = 0; q < 8; ++q) {
    const int j = tid + q * 512;
    unsigned u = __builtin_bit_cast(unsigned, row[j]);
    u ^= (unsigned)((int)u >> 31) | 0x80000000u;  // monotonic map
    ku[j] = ((unsigned long long)u << 32) | (unsigned)(SS - 1 - j);
  }
  __syncthreads();
  const int il = tid & 63;
  const int part = tid >> 6;  // j-eighth (wave-uniform)
  const int i = ic * 64 + il;
  const unsigned long long ki = ku[i];
  const ull2* kp = reinterpret_cast<const ull2*>(ku);
  int cnt = 0;
#pragma unroll 8
  for (int m = part * 256; m < part * 256 + 256; ++m) {
    ull2 v = kp[m];  // broadcast b128 read: 2 keys
    cnt += (int)(v.x > ki) + (int)(v.y > ki);
  }
  red[tid] = cnt;
  __syncthreads();
  if (tid < 64) {
    int tot = 0;
#pragma unroll
    for (int p = 0; p < 8; ++p) tot += red[tid + p * 64];
    if (tot < KTOP) out_idx[b * KTOP + tot] = (float)(ic * 64 + tid);
  }
}

// ---------------------------------------------------------------------------
// K3: fillBuffer-shaped writer, R15's indexing bug FIXED.
// A row = 4 windows x 1024 floats (256 f4). Grid = 4 batches x 4 windows x
// 256 row-chunks = 4096 blocks x 256 thr. Thread owns ONE f4 column
// (win*256+tid <= 1023), value from the 4KB window mask; 16 stores at
// uniform 16KB stride. Max f4 index = 16383*1024+1023 = 16,777,215 (in
// bounds); coverage 4096*256*16 = 16,777,216 f4 = PATTERN_N/4 exactly.
// ---------------------------------------------------------------------------
__global__ __launch_bounds__(256) void k3_pattern(
    const float* __restrict__ out_idx, float* __restrict__ pat) {
  __shared__ __align__(16) float mask[1024];  // this block's column window
  const int tid = threadIdx.x;
  const int b   = blockIdx.x >> 10;          // batch (0..3)
  const int win = (blockIdx.x >> 8) & 3;     // quarter-row window (0..3)
  const int rc  = blockIdx.x & 255;          // 16-row chunk (0..255)
  const int c0  = win * 1024;
  *reinterpret_cast<f4*>(&mask[tid * 4]) = (f4){0.f, 0.f, 0.f, 0.f};
  __syncthreads();
  if (tid < KTOP) {
    const int c = (int)out_idx[b * KTOP + tid] - c0;
    if ((unsigned)c < 1024u) mask[c] = 1.0f / (float)KTOP;
  }
  __syncthreads();
  const f4 v = *reinterpret_cast<const f4*>(&mask[tid * 4]);
  f4* p4 = reinterpret_cast<f4*>(pat) +
           ((size_t)b * SS + (size_t)rc * 16) * (SS / 4) + win * 256 + tid;
#pragma unroll 8
  for (int r = 0; r < 16; ++r) {
    p4[(size_t)r * (SS / 4)] = v;
  }
}

extern "C" void kernel_launch(void* const* d_in, const int* in_sizes, int n_in,
                              void* d_out, int out_size, void* d_ws,
                              size_t ws_size, hipStream_t stream) {
  const float* emb = (const float*)d_in[0];
  const float* W1  = (const float*)d_in[1];
  const float* b1  = (const float*)d_in[2];
  const float* W2  = (const float*)d_in[3];
  const float* b2  = (const float*)d_in[4];
  float* out = (float*)d_out;
  float* pat     = out;              // [B,S,S] pattern
  float* out_idx = out + PATTERN_N;  // [B,KTOP] indices as float
  float* scores = out + SCORES_OFF;
  _Float16* whf = (_Float16*)(out + WHF_OFF);
  _Float16* wlf = (_Float16*)(out + WLF_OFF);

  k0_wconv<<<dim3(32), dim3(256), 0, stream>>>(W1, whf, wlf);
  k1_mfma<<<dim3((BB * SS) / 64), dim3(256), 0, stream>>>(emb, whf, wlf, b1,
                                                          W2, b2, scores);
  k2_topk<<<dim3(BB * 64), dim3(512), 0, stream>>>(scores, out_idx);
  k3_pattern<<<dim3(4096), dim3(256), 0, stream>>>(out_idx, pat);
}